// Round 6
// baseline (12729.959 us; speedup 1.0000x reference)
//
#include <hip/hip_runtime.h>
#include <math.h>

// Problem constants
#define BB 2048
#define LL 100
#define FF 64
#define EE 256
#define DD 256
#define NOUT 3

#define COMP(v, i) ((i) == 0 ? (v).x : (i) == 1 ? (v).y : (i) == 2 ? (v).z : (v).w)

__device__ __forceinline__ float sigmoidf_(float x) {
    return 1.0f / (1.0f + expf(-x));
}
// tanh via identity 1 - 2/(1+e^{2x}); ~2e-7 abs fp32 error, saturates correctly.
__device__ __forceinline__ float tanhf_(float x) {
    return 1.0f - 2.0f / (1.0f + expf(2.0f * x));
}

// load 4 consecutive-k weight float4s (cols wcol..wcol+3) from a 1024-wide matrix
__device__ __forceinline__ void ldw4(float4 w[4], const float* __restrict__ base,
                                     int k, int wcol) {
    #pragma unroll
    for (int kk = 0; kk < 4; ++kk)
        w[kk] = *(const float4*)&base[(size_t)(k + kk) * 1024 + wcol];
}
// acc{0,1}[c] += e{0,1}[kk] * w[kk].c  (2 rows x 4 cols x 4 k)
__device__ __forceinline__ void fma8(float acc0[4], float acc1[4],
                                     const float4 w[4], float4 e0, float4 e1) {
    #pragma unroll
    for (int kk = 0; kk < 4; ++kk) {
        float a = COMP(e0, kk), b = COMP(e1, kk);
        acc0[0] += a * w[kk].x; acc0[1] += a * w[kk].y;
        acc0[2] += a * w[kk].z; acc0[3] += a * w[kk].w;
        acc1[0] += b * w[kk].x; acc1[1] += b * w[kk].y;
        acc1[2] += b * w[kk].z; acc1[3] += b * w[kk].w;
    }
}

// ---------------------------------------------------------------------------
// Encoder step: input attention + LSTM cell.
// grid (4 ns-slices, 128 row-groups of 16), 512 threads = 8 waves, R=2.
// 512 blocks -> 2 blocks/CU -> 4 waves/SIMD (LDS 24KB). Weights read as
// float4 col-quads with explicit A/B register double-buffering so the next
// chunk's loads are in flight during the current chunk's FMAs.
// ---------------------------------------------------------------------------
__global__ __launch_bounds__(512) void enc_step(
    const float* __restrict__ x,
    const float* __restrict__ Wa, const float* __restrict__ ba,
    const float* __restrict__ Wi, const float* __restrict__ Wh,
    const float* __restrict__ be,
    const float* __restrict__ h_in, float* __restrict__ h_out,
    float* __restrict__ c_st, int t, int first)
{
    __shared__ float h_s[16 * 256];   // 16 KB; aliased as gate staging in epilogue
    __shared__ float x_s[16 * 64];    // 4 KB
    __shared__ float ein_s[16 * 64];  // 4 KB

    const int ns   = blockIdx.x;
    const int row0 = blockIdx.y * 16;
    const int tid  = threadIdx.x;

    if (!first) {
        const float4* hg = (const float4*)(h_in + (size_t)row0 * 256);
        for (int i = tid; i < 1024; i += 512) ((float4*)h_s)[i] = hg[i];
    }
    if (tid < 256) {
        int r = tid >> 4, q = tid & 15;
        ((float4*)(x_s + r * 64))[q] =
            ((const float4*)(x + ((size_t)(row0 + r) * LL + t) * FF))[q];
    }
    __syncthreads();

    const int lane = tid & 63;
    const int w    = tid >> 6;    // wave 0..7
    const int rb   = w * 2;       // 2 rows per wave

    // ---- Phase A: input attention (f = lane), scalar weight prefetch ----
    {
        float a0, a1;
        a0 = a1 = ba[lane];
        float wA[4], wB[4];
        #pragma unroll
        for (int kk = 0; kk < 4; ++kk) wA[kk] = Wa[kk * 64 + lane];
        #pragma unroll
        for (int kp = 0; kp < 64; kp += 8) {
            #pragma unroll
            for (int kk = 0; kk < 4; ++kk) wB[kk] = Wa[(kp + 4 + kk) * 64 + lane];
            {
                float4 e0 = *(const float4*)&x_s[(rb + 0) * 64 + kp];
                float4 e1 = *(const float4*)&x_s[(rb + 1) * 64 + kp];
                #pragma unroll
                for (int kk = 0; kk < 4; ++kk) {
                    a0 += COMP(e0, kk) * wA[kk]; a1 += COMP(e1, kk) * wA[kk];
                }
            }
            if (kp + 8 < 64) {
                #pragma unroll
                for (int kk = 0; kk < 4; ++kk) wA[kk] = Wa[(kp + 8 + kk) * 64 + lane];
            } else if (!first) {
                #pragma unroll
                for (int kk = 0; kk < 4; ++kk) wA[kk] = Wa[(64 + kk) * 64 + lane];
            }
            {
                float4 e0 = *(const float4*)&x_s[(rb + 0) * 64 + kp + 4];
                float4 e1 = *(const float4*)&x_s[(rb + 1) * 64 + kp + 4];
                #pragma unroll
                for (int kk = 0; kk < 4; ++kk) {
                    a0 += COMP(e0, kk) * wB[kk]; a1 += COMP(e1, kk) * wB[kk];
                }
            }
        }
        if (!first) {
            #pragma unroll 4
            for (int kp = 0; kp < 256; kp += 8) {
                #pragma unroll
                for (int kk = 0; kk < 4; ++kk) wB[kk] = Wa[(64 + kp + 4 + kk) * 64 + lane];
                {
                    float4 e0 = *(const float4*)&h_s[(rb + 0) * 256 + kp];
                    float4 e1 = *(const float4*)&h_s[(rb + 1) * 256 + kp];
                    #pragma unroll
                    for (int kk = 0; kk < 4; ++kk) {
                        a0 += COMP(e0, kk) * wA[kk]; a1 += COMP(e1, kk) * wA[kk];
                    }
                }
                if (kp + 8 < 256) {
                    #pragma unroll
                    for (int kk = 0; kk < 4; ++kk) wA[kk] = Wa[(64 + kp + 8 + kk) * 64 + lane];
                }
                {
                    float4 e0 = *(const float4*)&h_s[(rb + 0) * 256 + kp + 4];
                    float4 e1 = *(const float4*)&h_s[(rb + 1) * 256 + kp + 4];
                    #pragma unroll
                    for (int kk = 0; kk < 4; ++kk) {
                        a0 += COMP(e0, kk) * wB[kk]; a1 += COMP(e1, kk) * wB[kk];
                    }
                }
            }
        }
        float av[2] = { a0, a1 };
        #pragma unroll
        for (int r = 0; r < 2; ++r) {
            float e = tanhf_(av[r]);
            float m = e;
            #pragma unroll
            for (int msk = 32; msk >= 1; msk >>= 1) m = fmaxf(m, __shfl_xor(m, msk, 64));
            float ev = expf(e - m);
            float s = ev;
            #pragma unroll
            for (int msk = 32; msk >= 1; msk >>= 1) s += __shfl_xor(s, msk, 64);
            ein_s[(rb + r) * 64 + lane] = (ev / s) * x_s[(rb + r) * 64 + lane];
        }
    }
    // no barrier: Phase B reads only this wave's own ein rows

    // ---- Phase B: gates. lane -> (unit-quad q, gate g), float4 weights ----
    const int q = lane & 15, g = lane >> 4;
    const int wcol = g * 256 + ns * 64 + q * 4;
    float acc0[4], acc1[4];
    {
        float4 b4 = *(const float4*)&be[wcol];
        acc0[0] = b4.x; acc0[1] = b4.y; acc0[2] = b4.z; acc0[3] = b4.w;
        acc1[0] = b4.x; acc1[1] = b4.y; acc1[2] = b4.z; acc1[3] = b4.w;
    }
    {
        float4 wA[4], wB[4];
        ldw4(wA, Wi, 0, wcol);
        #pragma unroll
        for (int kp = 0; kp < 64; kp += 8) {
            ldw4(wB, Wi, kp + 4, wcol);
            fma8(acc0, acc1, wA,
                 *(const float4*)&ein_s[(rb + 0) * 64 + kp],
                 *(const float4*)&ein_s[(rb + 1) * 64 + kp]);
            if (kp + 8 < 64) ldw4(wA, Wi, kp + 8, wcol);
            else if (!first) ldw4(wA, Wh, 0, wcol);
            fma8(acc0, acc1, wB,
                 *(const float4*)&ein_s[(rb + 0) * 64 + kp + 4],
                 *(const float4*)&ein_s[(rb + 1) * 64 + kp + 4]);
        }
        if (!first) {
            #pragma unroll 4
            for (int kp = 0; kp < 256; kp += 8) {
                ldw4(wB, Wh, kp + 4, wcol);
                fma8(acc0, acc1, wA,
                     *(const float4*)&h_s[(rb + 0) * 256 + kp],
                     *(const float4*)&h_s[(rb + 1) * 256 + kp]);
                if (kp + 8 < 256) ldw4(wA, Wh, kp + 8, wcol);
                fma8(acc0, acc1, wB,
                     *(const float4*)&h_s[(rb + 0) * 256 + kp + 4],
                     *(const float4*)&h_s[(rb + 1) * 256 + kp + 4]);
            }
        }
    }
    __syncthreads();              // all h_s reads done before aliasing
    float* gate_s = h_s;          // 4 gates x 16 rows x 64 units = 16 KB
    *(float4*)&gate_s[g * 1024 + (rb + 0) * 64 + q * 4] =
        make_float4(acc0[0], acc0[1], acc0[2], acc0[3]);
    *(float4*)&gate_s[g * 1024 + (rb + 1) * 64 + q * 4] =
        make_float4(acc1[0], acc1[1], acc1[2], acc1[3]);
    __syncthreads();

    // epilogue: lane = unit, wave handles its 2 rows
    #pragma unroll
    for (int r = 0; r < 2; ++r) {
        int row = rb + r;
        float gi_ = sigmoidf_(gate_s[           row * 64 + lane]);
        float gf_ = sigmoidf_(gate_s[1024 +     row * 64 + lane]);
        float gg_ = tanhf_  (gate_s[2048 +     row * 64 + lane]);
        float go_ = sigmoidf_(gate_s[3072 +     row * 64 + lane]);
        size_t ci = (size_t)(row0 + row) * 256 + ns * 64 + lane;
        float c_old = first ? 0.f : c_st[ci];
        float cn = gf_ * c_old + gi_ * gg_;
        c_st[ci]  = cn;
        h_out[ci] = go_ * tanhf_(cn);
    }
}

// ---------------------------------------------------------------------------
// Fused decoder attention scores, Lin=4 timesteps per accumulator set,
// with A/B register prefetch on the Wd stream.
// grid (B/16, 5), 256 threads.
// ---------------------------------------------------------------------------
#define SC_LIN 4
__global__ __launch_bounds__(256) void scores_fused(
    const float* __restrict__ enc_out, const float* __restrict__ Wd,
    const float* __restrict__ bd,
    const float* __restrict__ Wl, const float* __restrict__ bl,
    const float* __restrict__ hd, float* __restrict__ scores, int first)
{
    __shared__ float enc_s[SC_LIN * 16 * 256];   // 64 KB
    const int b0   = blockIdx.x * 16;
    const int l0   = blockIdx.y * 20;
    const int tid  = threadIdx.x;
    const int lane = tid & 63;
    const int rg   = tid >> 6;
    const int n0   = lane * 4;

    float hdp[4][4];
    {
        float4 bd4 = *(const float4*)&bd[n0];
        #pragma unroll
        for (int r = 0; r < 4; ++r) {
            hdp[r][0] = bd4.x; hdp[r][1] = bd4.y; hdp[r][2] = bd4.z; hdp[r][3] = bd4.w;
        }
    }
    if (!first) {
        for (int v = tid; v < 1024; v += 256) {
            int r = v >> 6, qq = v & 63;
            *(float4*)&enc_s[r * 256 + qq * 4] =
                *(const float4*)(hd + (size_t)(b0 + r) * 256 + qq * 4);
        }
        __syncthreads();
        const float* wb = Wd + 256 * 256;
        #pragma unroll 2
        for (int k = 0; k < 256; k += 4) {
            float4 hv[4];
            #pragma unroll
            for (int r = 0; r < 4; ++r) hv[r] = *(const float4*)&enc_s[(rg * 4 + r) * 256 + k];
            #pragma unroll
            for (int kk = 0; kk < 4; ++kk) {
                float4 wv = *(const float4*)&wb[(size_t)(k + kk) * 256 + n0];
                #pragma unroll
                for (int r = 0; r < 4; ++r) {
                    float e = COMP(hv[r], kk);
                    hdp[r][0] += e * wv.x; hdp[r][1] += e * wv.y;
                    hdp[r][2] += e * wv.z; hdp[r][3] += e * wv.w;
                }
            }
        }
        __syncthreads();
    }
    float4 wl4 = *(const float4*)&Wl[n0];
    const float blv = bl[0];

    for (int lo = 0; lo < 20; lo += SC_LIN) {
        for (int v = tid; v < SC_LIN * 16 * 64; v += 256) {
            int li = v >> 10, rem = v & 1023;
            int r = rem >> 6, qq = rem & 63;
            *(float4*)&enc_s[li * 4096 + r * 256 + qq * 4] =
                *(const float4*)(enc_out + (size_t)(l0 + lo + li) * (BB * 256)
                                 + (size_t)(b0 + r) * 256 + qq * 4);
        }
        __syncthreads();

        float acc[SC_LIN][4][4];
        #pragma unroll
        for (int li = 0; li < SC_LIN; ++li)
            #pragma unroll
            for (int r = 0; r < 4; ++r)
                #pragma unroll
                for (int c = 0; c < 4; ++c) acc[li][r][c] = hdp[r][c];

        float4 wA[4], wB[4];
        #pragma unroll
        for (int kk = 0; kk < 4; ++kk)
            wA[kk] = *(const float4*)&Wd[(size_t)kk * 256 + n0];
        for (int kp = 0; kp < 256; kp += 8) {
            #pragma unroll
            for (int kk = 0; kk < 4; ++kk)
                wB[kk] = *(const float4*)&Wd[(size_t)(kp + 4 + kk) * 256 + n0];
            #pragma unroll
            for (int li = 0; li < SC_LIN; ++li) {
                float4 ev[4];
                #pragma unroll
                for (int r = 0; r < 4; ++r)
                    ev[r] = *(const float4*)&enc_s[li * 4096 + (rg * 4 + r) * 256 + kp];
                #pragma unroll
                for (int kk = 0; kk < 4; ++kk) {
                    #pragma unroll
                    for (int r = 0; r < 4; ++r) {
                        float e = COMP(ev[r], kk);
                        acc[li][r][0] += e * wA[kk].x; acc[li][r][1] += e * wA[kk].y;
                        acc[li][r][2] += e * wA[kk].z; acc[li][r][3] += e * wA[kk].w;
                    }
                }
            }
            if (kp + 8 < 256) {
                #pragma unroll
                for (int kk = 0; kk < 4; ++kk)
                    wA[kk] = *(const float4*)&Wd[(size_t)(kp + 8 + kk) * 256 + n0];
            }
            #pragma unroll
            for (int li = 0; li < SC_LIN; ++li) {
                float4 ev[4];
                #pragma unroll
                for (int r = 0; r < 4; ++r)
                    ev[r] = *(const float4*)&enc_s[li * 4096 + (rg * 4 + r) * 256 + kp + 4];
                #pragma unroll
                for (int kk = 0; kk < 4; ++kk) {
                    #pragma unroll
                    for (int r = 0; r < 4; ++r) {
                        float e = COMP(ev[r], kk);
                        acc[li][r][0] += e * wB[kk].x; acc[li][r][1] += e * wB[kk].y;
                        acc[li][r][2] += e * wB[kk].z; acc[li][r][3] += e * wB[kk].w;
                    }
                }
            }
        }
        #pragma unroll
        for (int li = 0; li < SC_LIN; ++li) {
            #pragma unroll
            for (int r = 0; r < 4; ++r) {
                float p = tanhf_(acc[li][r][0]) * wl4.x + tanhf_(acc[li][r][1]) * wl4.y
                        + tanhf_(acc[li][r][2]) * wl4.z + tanhf_(acc[li][r][3]) * wl4.w;
                #pragma unroll
                for (int msk = 32; msk >= 1; msk >>= 1) p += __shfl_xor(p, msk, 64);
                if (lane == 0)
                    scores[(size_t)(l0 + lo + li) * BB + b0 + rg * 4 + r] = p + blv;
            }
        }
        __syncthreads();
    }
}

// ---------------------------------------------------------------------------
// softmax over L + ctx from scores buffer. Block = 8 rows.
// ---------------------------------------------------------------------------
__global__ __launch_bounds__(256) void softmax_ctx(
    const float* __restrict__ scores, const float* __restrict__ enc_out,
    float* __restrict__ ctx)
{
    __shared__ float al_s[8 * 100];
    const int b0  = blockIdx.x * 8;
    const int tid = threadIdx.x;
    for (int v = tid; v < 800; v += 256) {
        int r = v / 100, l = v - r * 100;
        al_s[r * 100 + l] = scores[(size_t)l * BB + b0 + r];
    }
    __syncthreads();
    if (tid < 8) {
        float m = -1e30f;
        for (int l = 0; l < LL; ++l) m = fmaxf(m, al_s[tid * 100 + l]);
        float s = 0.f;
        for (int l = 0; l < LL; ++l) { float e = expf(al_s[tid * 100 + l] - m); al_s[tid * 100 + l] = e; s += e; }
        float inv = 1.f / s;
        for (int l = 0; l < LL; ++l) al_s[tid * 100 + l] *= inv;
    }
    __syncthreads();
    float acc[8] = {};
    for (int l = 0; l < LL; ++l) {
        const float* er = enc_out + (size_t)l * (BB * 256) + (size_t)b0 * 256 + tid;
        #pragma unroll
        for (int r = 0; r < 8; ++r) acc[r] += al_s[r * 100 + l] * er[r * 256];
    }
    for (int r = 0; r < 8; ++r) ctx[(size_t)(b0 + r) * 256 + tid] = acc[r];
}

// ---------------------------------------------------------------------------
// Decoder LSTM cell: R=8 / 4-gates-in-lane. grid (4, 64), 256 threads.
// ---------------------------------------------------------------------------
__global__ __launch_bounds__(256) void dec_step(
    const float* __restrict__ ctxp,
    const float* __restrict__ Wdi, const float* __restrict__ Wdh,
    const float* __restrict__ bdec,
    const float* __restrict__ hd_in, float* __restrict__ hd_out,
    float* __restrict__ c_st, int first)
{
    __shared__ float ct_s[32 * 256];
    __shared__ float hd_s[32 * 256];
    const int ns   = blockIdx.x;
    const int row0 = blockIdx.y * 32;
    const int tid  = threadIdx.x;
    {
        const float4* cg = (const float4*)(ctxp + (size_t)row0 * 256);
        for (int i = tid; i < 2048; i += 256) ((float4*)ct_s)[i] = cg[i];
    }
    if (!first) {
        const float4* hg = (const float4*)(hd_in + (size_t)row0 * 256);
        for (int i = tid; i < 2048; i += 256) ((float4*)hd_s)[i] = hg[i];
    }
    __syncthreads();
    const int lane = tid & 63, w = tid >> 6, rb = w * 8;
    const int j = ns * 64 + lane;
    float acc[8][4];
    {
        float b0 = bdec[j], b1 = bdec[256 + j], b2 = bdec[512 + j], b3 = bdec[768 + j];
        #pragma unroll
        for (int r = 0; r < 8; ++r) {
            acc[r][0] = b0; acc[r][1] = b1; acc[r][2] = b2; acc[r][3] = b3;
        }
    }
    #pragma unroll 2
    for (int k = 0; k < 256; k += 4) {
        float4 cv[8];
        #pragma unroll
        for (int r = 0; r < 8; ++r) cv[r] = *(const float4*)&ct_s[(rb + r) * 256 + k];
        #pragma unroll
        for (int kk = 0; kk < 4; ++kk) {
            const float* wp = Wdi + (size_t)(k + kk) * 1024 + j;
            float w0 = wp[0], w1 = wp[256], w2 = wp[512], w3 = wp[768];
            #pragma unroll
            for (int r = 0; r < 8; ++r) {
                float e = COMP(cv[r], kk);
                acc[r][0] += e * w0; acc[r][1] += e * w1;
                acc[r][2] += e * w2; acc[r][3] += e * w3;
            }
        }
    }
    if (!first) {
        #pragma unroll 2
        for (int k = 0; k < 256; k += 4) {
            float4 hv[8];
            #pragma unroll
            for (int r = 0; r < 8; ++r) hv[r] = *(const float4*)&hd_s[(rb + r) * 256 + k];
            #pragma unroll
            for (int kk = 0; kk < 4; ++kk) {
                const float* wp = Wdh + (size_t)(k + kk) * 1024 + j;
                float w0 = wp[0], w1 = wp[256], w2 = wp[512], w3 = wp[768];
                #pragma unroll
                for (int r = 0; r < 8; ++r) {
                    float e = COMP(hv[r], kk);
                    acc[r][0] += e * w0; acc[r][1] += e * w1;
                    acc[r][2] += e * w2; acc[r][3] += e * w3;
                }
            }
        }
    }
    #pragma unroll
    for (int r = 0; r < 8; ++r) {
        size_t ci = (size_t)(row0 + rb + r) * 256 + j;
        float c_old = first ? 0.f : c_st[ci];
        float gi_ = sigmoidf_(acc[r][0]);
        float gf_ = sigmoidf_(acc[r][1]);
        float gg_ = tanhf_  (acc[r][2]);
        float go_ = sigmoidf_(acc[r][3]);
        float cn = gf_ * c_old + gi_ * gg_;
        c_st[ci]   = cn;
        hd_out[ci] = go_ * tanhf_(cn);
    }
}

// ---------------------------------------------------------------------------
// Head: fc = tanh(h_d@Wf+bf); out[:,step] = tanh(fc@Wo+bo). Block = 16 rows.
// ---------------------------------------------------------------------------
__global__ __launch_bounds__(256) void head_k(
    const float* __restrict__ hd, const float* __restrict__ Wf,
    const float* __restrict__ bf, const float* __restrict__ Wo,
    const float* __restrict__ bo, float* __restrict__ out, int step)
{
    __shared__ float hd_s[16 * 256];
    __shared__ float fc_s[16 * 128];
    const int b0  = blockIdx.x * 16;
    const int tid = threadIdx.x;
    {
        const float4* hg = (const float4*)(hd + (size_t)b0 * 256);
        for (int i = tid; i < 1024; i += 256) ((float4*)hd_s)[i] = hg[i];
    }
    __syncthreads();
    {
        const int f = tid & 127, rg = tid >> 7;
        float acc[8];
        float bfv = bf[f];
        #pragma unroll
        for (int rr = 0; rr < 8; ++rr) acc[rr] = bfv;
        const float* wp = Wf + f;
        #pragma unroll 2
        for (int k = 0; k < 256; ++k) {
            float wv = wp[k * 128];
            #pragma unroll
            for (int rr = 0; rr < 8; ++rr) acc[rr] += hd_s[(rg * 8 + rr) * 256 + k] * wv;
        }
        for (int rr = 0; rr < 8; ++rr) fc_s[(rg * 8 + rr) * 128 + f] = tanhf_(acc[rr]);
    }
    __syncthreads();
    {
        const int lane = tid & 63, w = tid >> 6;
        const float bov = bo[0];
        #pragma unroll
        for (int rr = 0; rr < 4; ++rr) {
            int r = w * 4 + rr;
            float p = fc_s[r * 128 + lane] * Wo[lane] + fc_s[r * 128 + 64 + lane] * Wo[64 + lane];
            #pragma unroll
            for (int msk = 32; msk >= 1; msk >>= 1) p += __shfl_xor(p, msk, 64);
            if (lane == 0) out[(size_t)(b0 + r) * NOUT + step] = tanhf_(p + bov);
        }
    }
}

extern "C" void kernel_launch(void* const* d_in, const int* in_sizes, int n_in,
                              void* d_out, int out_size, void* d_ws, size_t ws_size,
                              hipStream_t stream)
{
    const float* x    = (const float*)d_in[0];
    const float* Wa   = (const float*)d_in[1];
    const float* ba   = (const float*)d_in[2];
    const float* Wi   = (const float*)d_in[3];
    const float* Wh   = (const float*)d_in[4];
    const float* be   = (const float*)d_in[5];
    const float* Wd   = (const float*)d_in[6];
    const float* bd   = (const float*)d_in[7];
    const float* Wl   = (const float*)d_in[8];
    const float* bl   = (const float*)d_in[9];
    const float* Wdi  = (const float*)d_in[10];
    const float* Wdh  = (const float*)d_in[11];
    const float* bdec = (const float*)d_in[12];
    const float* Wf   = (const float*)d_in[13];
    const float* bf   = (const float*)d_in[14];
    const float* Wo   = (const float*)d_in[15];
    const float* bo   = (const float*)d_in[16];
    float* out = (float*)d_out;

    // ws layout (floats): enc_out | c_enc | hd0 | hd1 | c_d | ctx | scores  (~221 MB)
    const size_t f_enc    = (size_t)LL * BB * EE;
    const size_t f_state  = (size_t)BB * EE;
    const size_t f_scores = (size_t)LL * BB;
    const size_t base_f   = f_enc + 5 * f_state + f_scores;

    float* ws      = (float*)d_ws;
    float* enc_out = ws;
    float* c_enc   = enc_out + f_enc;
    float* hd0     = c_enc + f_state;
    float* hd1     = hd0 + f_state;
    float* c_d     = hd1 + f_state;
    float* ctx     = c_d + f_state;
    float* scores  = ctx + f_state;

    if (ws_size < base_f * sizeof(float)) return;   // diagnostic clean-fail

    dim3 egrid(4, 128);
    for (int t = 0; t < LL; ++t) {
        const float* h_in = (t == 0) ? enc_out : enc_out + (size_t)(t - 1) * BB * EE;
        float* h_out = enc_out + (size_t)t * BB * EE;
        enc_step<<<egrid, 512, 0, stream>>>(x, Wa, ba, Wi, Wh, be,
                                            h_in, h_out, c_enc, t, t == 0 ? 1 : 0);
    }

    float* hbuf[2] = { hd0, hd1 };
    for (int s = 0; s < NOUT; ++s) {
        const float* hd_in = (s == 0) ? hd0 : hbuf[(s + 1) & 1];
        float* hd_out = hbuf[s & 1];
        scores_fused<<<dim3(BB / 16, 5), 256, 0, stream>>>(
            enc_out, Wd, bd, Wl, bl, hd_in, scores, s == 0);
        softmax_ctx<<<BB / 8, 256, 0, stream>>>(scores, enc_out, ctx);
        dec_step<<<dim3(4, 64), 256, 0, stream>>>(ctx, Wdi, Wdh, bdec, hd_in, hd_out, c_d, s == 0);
        head_k<<<BB / 16, 256, 0, stream>>>(hd_out, Wf, bf, Wo, bo, out, s);
    }
}

// Round 7
// 5617.002 us; speedup vs baseline: 2.2663x; 2.2663x over previous
//
#include <hip/hip_runtime.h>
#include <math.h>

// Problem constants
#define BB 2048
#define LL 100
#define FF 64
#define EE 256
#define DD 256
#define NOUT 3

#define COMP(v, i) ((i) == 0 ? (v).x : (i) == 1 ? (v).y : (i) == 2 ? (v).z : (v).w)

__device__ __forceinline__ float sigmoidf_(float x) {
    return 1.0f / (1.0f + expf(-x));
}
// tanh via identity 1 - 2/(1+e^{2x}); ~2e-7 abs fp32 error, saturates correctly.
__device__ __forceinline__ float tanhf_(float x) {
    return 1.0f - 2.0f / (1.0f + expf(2.0f * x));
}

// ---------------------------------------------------------------------------
// Persistent encoder: ONE kernel runs all 100 timesteps.
// The LSTM+input-attention recurrence is row-local (h[b],c[b] depend only on
// x[b,t,:] and the same row's previous state), so blocks never communicate.
// grid 256 blocks x 512 threads; block owns 8 batch rows for the whole run.
//  - attention: wave w computes row w (lane = feature col), softmax via shuffle
//  - gates: thread owns cols (tid, tid+512) across all 8 rows; weights
//    coalesced from L2 (256 blocks x 1.31MB = 336MB/step ~ 9.8us/XCD-L2),
//    activations broadcast from LDS
//  - epilogue: thread owns (unit u=tid&255, rows (tid>>8)*4..+3); c in regs
// 3 __syncthreads per step; h never leaves the CU (only enc_out is written).
// ---------------------------------------------------------------------------
__global__ __launch_bounds__(512) void enc_all(
    const float* __restrict__ x,
    const float* __restrict__ Wa, const float* __restrict__ ba,
    const float* __restrict__ Wi, const float* __restrict__ Wh,
    const float* __restrict__ be,
    float* __restrict__ enc_out)
{
    __shared__ float h_s[8 * 256];      // 8 KB  current h
    __shared__ float x_s[8 * 64];       // 2 KB  x_t
    __shared__ float ein_s[8 * 64];     // 2 KB  attended input
    __shared__ float gate_s[8 * 1024];  // 32 KB gate staging

    const int row0 = blockIdx.x * 8;
    const int tid  = threadIdx.x;
    const int lane = tid & 63;
    const int w    = tid >> 6;           // wave 0..7 == attention row

    const int c0 = tid;                  // gate cols owned by this thread
    const int c1 = tid + 512;

    const int u   = tid & 255;           // epilogue unit
    const int er0 = (tid >> 8) * 4;      // epilogue rows er0..er0+3
    float c_reg[4] = {0.f, 0.f, 0.f, 0.f};

    const float bav = ba[lane];
    const float be0 = be[c0], be1 = be[c1];

    for (int t = 0; t < LL; ++t) {
        // ---- stage x_t: wave w loads its own row (same-wave LDS dependency) ----
        x_s[w * 64 + lane] = x[((size_t)(row0 + w) * LL + t) * FF + lane];

        // ---- input attention: wave w -> row w, lane -> feature col ----
        {
            float a = bav;
            #pragma unroll 4
            for (int k4 = 0; k4 < 64; k4 += 4) {
                float4 xa = *(const float4*)&x_s[w * 64 + k4];
                a += xa.x * Wa[(size_t)(k4 + 0) * 64 + lane]
                   + xa.y * Wa[(size_t)(k4 + 1) * 64 + lane]
                   + xa.z * Wa[(size_t)(k4 + 2) * 64 + lane]
                   + xa.w * Wa[(size_t)(k4 + 3) * 64 + lane];
            }
            if (t > 0) {
                #pragma unroll 4
                for (int k4 = 0; k4 < 256; k4 += 4) {
                    float4 ha = *(const float4*)&h_s[w * 256 + k4];
                    a += ha.x * Wa[(size_t)(64 + k4 + 0) * 64 + lane]
                       + ha.y * Wa[(size_t)(64 + k4 + 1) * 64 + lane]
                       + ha.z * Wa[(size_t)(64 + k4 + 2) * 64 + lane]
                       + ha.w * Wa[(size_t)(64 + k4 + 3) * 64 + lane];
                }
            }
            float e = tanhf_(a);
            float m = e;
            #pragma unroll
            for (int msk = 32; msk >= 1; msk >>= 1) m = fmaxf(m, __shfl_xor(m, msk, 64));
            float ev = expf(e - m);
            float s = ev;
            #pragma unroll
            for (int msk = 32; msk >= 1; msk >>= 1) s += __shfl_xor(s, msk, 64);
            ein_s[w * 64 + lane] = (ev / s) * x_s[w * 64 + lane];
        }
        __syncthreads();   // ein ready for all rows

        // ---- gates: thread computes cols c0,c1 for all 8 rows ----
        float acc0[8], acc1[8];
        #pragma unroll
        for (int r = 0; r < 8; ++r) { acc0[r] = be0; acc1[r] = be1; }

        #pragma unroll 4
        for (int k4 = 0; k4 < 64; k4 += 4) {
            float4 ev[8];
            #pragma unroll
            for (int r = 0; r < 8; ++r) ev[r] = *(const float4*)&ein_s[r * 64 + k4];
            #pragma unroll
            for (int kk = 0; kk < 4; ++kk) {
                float w0 = Wi[(size_t)(k4 + kk) * 1024 + c0];
                float w1 = Wi[(size_t)(k4 + kk) * 1024 + c1];
                #pragma unroll
                for (int r = 0; r < 8; ++r) {
                    float e = COMP(ev[r], kk);
                    acc0[r] += e * w0; acc1[r] += e * w1;
                }
            }
        }
        if (t > 0) {
            #pragma unroll 4
            for (int k4 = 0; k4 < 256; k4 += 4) {
                float4 hv[8];
                #pragma unroll
                for (int r = 0; r < 8; ++r) hv[r] = *(const float4*)&h_s[r * 256 + k4];
                #pragma unroll
                for (int kk = 0; kk < 4; ++kk) {
                    float w0 = Wh[(size_t)(k4 + kk) * 1024 + c0];
                    float w1 = Wh[(size_t)(k4 + kk) * 1024 + c1];
                    #pragma unroll
                    for (int r = 0; r < 8; ++r) {
                        float e = COMP(hv[r], kk);
                        acc0[r] += e * w0; acc1[r] += e * w1;
                    }
                }
            }
        }
        #pragma unroll
        for (int r = 0; r < 8; ++r) {
            gate_s[r * 1024 + c0] = acc0[r];
            gate_s[r * 1024 + c1] = acc1[r];
        }
        __syncthreads();   // gates staged; all h_s/ein_s reads complete

        // ---- epilogue: thread -> (unit u, rows er0..er0+3), c in registers ----
        #pragma unroll
        for (int rr = 0; rr < 4; ++rr) {
            int r = er0 + rr;
            float gi_ = sigmoidf_(gate_s[r * 1024 + u]);
            float gf_ = sigmoidf_(gate_s[r * 1024 + 256 + u]);
            float gg_ = tanhf_  (gate_s[r * 1024 + 512 + u]);
            float go_ = sigmoidf_(gate_s[r * 1024 + 768 + u]);
            float cn = gf_ * c_reg[rr] + gi_ * gg_;
            c_reg[rr] = cn;
            float hn = go_ * tanhf_(cn);
            h_s[r * 256 + u] = hn;
            enc_out[((size_t)t * BB + row0 + r) * 256 + u] = hn;
        }
        __syncthreads();   // h ready for next step
    }
}

// ---------------------------------------------------------------------------
// Fused decoder attention scores, Lin=4 timesteps per accumulator set.
// grid (B/16, 5), 256 threads.
// ---------------------------------------------------------------------------
#define SC_LIN 4
__global__ __launch_bounds__(256) void scores_fused(
    const float* __restrict__ enc_out, const float* __restrict__ Wd,
    const float* __restrict__ bd,
    const float* __restrict__ Wl, const float* __restrict__ bl,
    const float* __restrict__ hd, float* __restrict__ scores, int first)
{
    __shared__ float enc_s[SC_LIN * 16 * 256];   // 64 KB
    const int b0   = blockIdx.x * 16;
    const int l0   = blockIdx.y * 20;
    const int tid  = threadIdx.x;
    const int lane = tid & 63;
    const int rg   = tid >> 6;
    const int n0   = lane * 4;

    float hdp[4][4];
    {
        float4 bd4 = *(const float4*)&bd[n0];
        #pragma unroll
        for (int r = 0; r < 4; ++r) {
            hdp[r][0] = bd4.x; hdp[r][1] = bd4.y; hdp[r][2] = bd4.z; hdp[r][3] = bd4.w;
        }
    }
    if (!first) {
        for (int v = tid; v < 1024; v += 256) {
            int r = v >> 6, qq = v & 63;
            *(float4*)&enc_s[r * 256 + qq * 4] =
                *(const float4*)(hd + (size_t)(b0 + r) * 256 + qq * 4);
        }
        __syncthreads();
        const float* wb = Wd + 256 * 256;
        #pragma unroll 2
        for (int k = 0; k < 256; k += 4) {
            float4 hv[4];
            #pragma unroll
            for (int r = 0; r < 4; ++r) hv[r] = *(const float4*)&enc_s[(rg * 4 + r) * 256 + k];
            #pragma unroll
            for (int kk = 0; kk < 4; ++kk) {
                float4 wv = *(const float4*)&wb[(size_t)(k + kk) * 256 + n0];
                #pragma unroll
                for (int r = 0; r < 4; ++r) {
                    float e = COMP(hv[r], kk);
                    hdp[r][0] += e * wv.x; hdp[r][1] += e * wv.y;
                    hdp[r][2] += e * wv.z; hdp[r][3] += e * wv.w;
                }
            }
        }
        __syncthreads();
    }
    float4 wl4 = *(const float4*)&Wl[n0];
    const float blv = bl[0];

    for (int lo = 0; lo < 20; lo += SC_LIN) {
        for (int v = tid; v < SC_LIN * 16 * 64; v += 256) {
            int li = v >> 10, rem = v & 1023;
            int r = rem >> 6, qq = rem & 63;
            *(float4*)&enc_s[li * 4096 + r * 256 + qq * 4] =
                *(const float4*)(enc_out + (size_t)(l0 + lo + li) * (BB * 256)
                                 + (size_t)(b0 + r) * 256 + qq * 4);
        }
        __syncthreads();

        float acc[SC_LIN][4][4];
        #pragma unroll
        for (int li = 0; li < SC_LIN; ++li)
            #pragma unroll
            for (int r = 0; r < 4; ++r)
                #pragma unroll
                for (int c = 0; c < 4; ++c) acc[li][r][c] = hdp[r][c];

        for (int k = 0; k < 256; k += 4) {
            float4 wv[4];
            #pragma unroll
            for (int kk = 0; kk < 4; ++kk)
                wv[kk] = *(const float4*)&Wd[(size_t)(k + kk) * 256 + n0];
            #pragma unroll
            for (int li = 0; li < SC_LIN; ++li) {
                float4 ev[4];
                #pragma unroll
                for (int r = 0; r < 4; ++r)
                    ev[r] = *(const float4*)&enc_s[li * 4096 + (rg * 4 + r) * 256 + k];
                #pragma unroll
                for (int kk = 0; kk < 4; ++kk) {
                    #pragma unroll
                    for (int r = 0; r < 4; ++r) {
                        float e = COMP(ev[r], kk);
                        acc[li][r][0] += e * wv[kk].x; acc[li][r][1] += e * wv[kk].y;
                        acc[li][r][2] += e * wv[kk].z; acc[li][r][3] += e * wv[kk].w;
                    }
                }
            }
        }
        #pragma unroll
        for (int li = 0; li < SC_LIN; ++li) {
            #pragma unroll
            for (int r = 0; r < 4; ++r) {
                float p = tanhf_(acc[li][r][0]) * wl4.x + tanhf_(acc[li][r][1]) * wl4.y
                        + tanhf_(acc[li][r][2]) * wl4.z + tanhf_(acc[li][r][3]) * wl4.w;
                #pragma unroll
                for (int msk = 32; msk >= 1; msk >>= 1) p += __shfl_xor(p, msk, 64);
                if (lane == 0)
                    scores[(size_t)(l0 + lo + li) * BB + b0 + rg * 4 + r] = p + blv;
            }
        }
        __syncthreads();
    }
}

// ---------------------------------------------------------------------------
// softmax over L + ctx from scores buffer. Block = 8 rows.
// ---------------------------------------------------------------------------
__global__ __launch_bounds__(256) void softmax_ctx(
    const float* __restrict__ scores, const float* __restrict__ enc_out,
    float* __restrict__ ctx)
{
    __shared__ float al_s[8 * 100];
    const int b0  = blockIdx.x * 8;
    const int tid = threadIdx.x;
    for (int v = tid; v < 800; v += 256) {
        int r = v / 100, l = v - r * 100;
        al_s[r * 100 + l] = scores[(size_t)l * BB + b0 + r];
    }
    __syncthreads();
    if (tid < 8) {
        float m = -1e30f;
        for (int l = 0; l < LL; ++l) m = fmaxf(m, al_s[tid * 100 + l]);
        float s = 0.f;
        for (int l = 0; l < LL; ++l) { float e = expf(al_s[tid * 100 + l] - m); al_s[tid * 100 + l] = e; s += e; }
        float inv = 1.f / s;
        for (int l = 0; l < LL; ++l) al_s[tid * 100 + l] *= inv;
    }
    __syncthreads();
    float acc[8] = {};
    for (int l = 0; l < LL; ++l) {
        const float* er = enc_out + (size_t)l * (BB * 256) + (size_t)b0 * 256 + tid;
        #pragma unroll
        for (int r = 0; r < 8; ++r) acc[r] += al_s[r * 100 + l] * er[r * 256];
    }
    for (int r = 0; r < 8; ++r) ctx[(size_t)(b0 + r) * 256 + tid] = acc[r];
}

// ---------------------------------------------------------------------------
// Decoder LSTM cell: R=8 / 4-gates-in-lane. grid (4, 64), 256 threads.
// ---------------------------------------------------------------------------
__global__ __launch_bounds__(256) void dec_step(
    const float* __restrict__ ctxp,
    const float* __restrict__ Wdi, const float* __restrict__ Wdh,
    const float* __restrict__ bdec,
    const float* __restrict__ hd_in, float* __restrict__ hd_out,
    float* __restrict__ c_st, int first)
{
    __shared__ float ct_s[32 * 256];
    __shared__ float hd_s[32 * 256];
    const int ns   = blockIdx.x;
    const int row0 = blockIdx.y * 32;
    const int tid  = threadIdx.x;
    {
        const float4* cg = (const float4*)(ctxp + (size_t)row0 * 256);
        for (int i = tid; i < 2048; i += 256) ((float4*)ct_s)[i] = cg[i];
    }
    if (!first) {
        const float4* hg = (const float4*)(hd_in + (size_t)row0 * 256);
        for (int i = tid; i < 2048; i += 256) ((float4*)hd_s)[i] = hg[i];
    }
    __syncthreads();
    const int lane = tid & 63, w = tid >> 6, rb = w * 8;
    const int j = ns * 64 + lane;
    float acc[8][4];
    {
        float b0 = bdec[j], b1 = bdec[256 + j], b2 = bdec[512 + j], b3 = bdec[768 + j];
        #pragma unroll
        for (int r = 0; r < 8; ++r) {
            acc[r][0] = b0; acc[r][1] = b1; acc[r][2] = b2; acc[r][3] = b3;
        }
    }
    #pragma unroll 2
    for (int k = 0; k < 256; k += 4) {
        float4 cv[8];
        #pragma unroll
        for (int r = 0; r < 8; ++r) cv[r] = *(const float4*)&ct_s[(rb + r) * 256 + k];
        #pragma unroll
        for (int kk = 0; kk < 4; ++kk) {
            const float* wp = Wdi + (size_t)(k + kk) * 1024 + j;
            float w0 = wp[0], w1 = wp[256], w2 = wp[512], w3 = wp[768];
            #pragma unroll
            for (int r = 0; r < 8; ++r) {
                float e = COMP(cv[r], kk);
                acc[r][0] += e * w0; acc[r][1] += e * w1;
                acc[r][2] += e * w2; acc[r][3] += e * w3;
            }
        }
    }
    if (!first) {
        #pragma unroll 2
        for (int k = 0; k < 256; k += 4) {
            float4 hv[8];
            #pragma unroll
            for (int r = 0; r < 8; ++r) hv[r] = *(const float4*)&hd_s[(rb + r) * 256 + k];
            #pragma unroll
            for (int kk = 0; kk < 4; ++kk) {
                const float* wp = Wdh + (size_t)(k + kk) * 1024 + j;
                float w0 = wp[0], w1 = wp[256], w2 = wp[512], w3 = wp[768];
                #pragma unroll
                for (int r = 0; r < 8; ++r) {
                    float e = COMP(hv[r], kk);
                    acc[r][0] += e * w0; acc[r][1] += e * w1;
                    acc[r][2] += e * w2; acc[r][3] += e * w3;
                }
            }
        }
    }
    #pragma unroll
    for (int r = 0; r < 8; ++r) {
        size_t ci = (size_t)(row0 + rb + r) * 256 + j;
        float c_old = first ? 0.f : c_st[ci];
        float gi_ = sigmoidf_(acc[r][0]);
        float gf_ = sigmoidf_(acc[r][1]);
        float gg_ = tanhf_  (acc[r][2]);
        float go_ = sigmoidf_(acc[r][3]);
        float cn = gf_ * c_old + gi_ * gg_;
        c_st[ci]   = cn;
        hd_out[ci] = go_ * tanhf_(cn);
    }
}

// ---------------------------------------------------------------------------
// Head: fc = tanh(h_d@Wf+bf); out[:,step] = tanh(fc@Wo+bo). Block = 16 rows.
// ---------------------------------------------------------------------------
__global__ __launch_bounds__(256) void head_k(
    const float* __restrict__ hd, const float* __restrict__ Wf,
    const float* __restrict__ bf, const float* __restrict__ Wo,
    const float* __restrict__ bo, float* __restrict__ out, int step)
{
    __shared__ float hd_s[16 * 256];
    __shared__ float fc_s[16 * 128];
    const int b0  = blockIdx.x * 16;
    const int tid = threadIdx.x;
    {
        const float4* hg = (const float4*)(hd + (size_t)b0 * 256);
        for (int i = tid; i < 1024; i += 256) ((float4*)hd_s)[i] = hg[i];
    }
    __syncthreads();
    {
        const int f = tid & 127, rg = tid >> 7;
        float acc[8];
        float bfv = bf[f];
        #pragma unroll
        for (int rr = 0; rr < 8; ++rr) acc[rr] = bfv;
        const float* wp = Wf + f;
        #pragma unroll 2
        for (int k = 0; k < 256; ++k) {
            float wv = wp[k * 128];
            #pragma unroll
            for (int rr = 0; rr < 8; ++rr) acc[rr] += hd_s[(rg * 8 + rr) * 256 + k] * wv;
        }
        for (int rr = 0; rr < 8; ++rr) fc_s[(rg * 8 + rr) * 128 + f] = tanhf_(acc[rr]);
    }
    __syncthreads();
    {
        const int lane = tid & 63, w = tid >> 6;
        const float bov = bo[0];
        #pragma unroll
        for (int rr = 0; rr < 4; ++rr) {
            int r = w * 4 + rr;
            float p = fc_s[r * 128 + lane] * Wo[lane] + fc_s[r * 128 + 64 + lane] * Wo[64 + lane];
            #pragma unroll
            for (int msk = 32; msk >= 1; msk >>= 1) p += __shfl_xor(p, msk, 64);
            if (lane == 0) out[(size_t)(b0 + r) * NOUT + step] = tanhf_(p + bov);
        }
    }
}

extern "C" void kernel_launch(void* const* d_in, const int* in_sizes, int n_in,
                              void* d_out, int out_size, void* d_ws, size_t ws_size,
                              hipStream_t stream)
{
    const float* x    = (const float*)d_in[0];
    const float* Wa   = (const float*)d_in[1];
    const float* ba   = (const float*)d_in[2];
    const float* Wi   = (const float*)d_in[3];
    const float* Wh   = (const float*)d_in[4];
    const float* be   = (const float*)d_in[5];
    const float* Wd   = (const float*)d_in[6];
    const float* bd   = (const float*)d_in[7];
    const float* Wl   = (const float*)d_in[8];
    const float* bl   = (const float*)d_in[9];
    const float* Wdi  = (const float*)d_in[10];
    const float* Wdh  = (const float*)d_in[11];
    const float* bdec = (const float*)d_in[12];
    const float* Wf   = (const float*)d_in[13];
    const float* bf   = (const float*)d_in[14];
    const float* Wo   = (const float*)d_in[15];
    const float* bo   = (const float*)d_in[16];
    float* out = (float*)d_out;

    // ws layout (floats): enc_out | c_enc(unused) | hd0 | hd1 | c_d | ctx | scores
    const size_t f_enc    = (size_t)LL * BB * EE;
    const size_t f_state  = (size_t)BB * EE;
    const size_t f_scores = (size_t)LL * BB;
    const size_t base_f   = f_enc + 5 * f_state + f_scores;

    float* ws      = (float*)d_ws;
    float* enc_out = ws;
    float* c_enc   = enc_out + f_enc;
    float* hd0     = c_enc + f_state;
    float* hd1     = hd0 + f_state;
    float* c_d     = hd1 + f_state;
    float* ctx     = c_d + f_state;
    float* scores  = ctx + f_state;

    if (ws_size < base_f * sizeof(float)) return;   // diagnostic clean-fail

    // persistent encoder: one dispatch for all 100 timesteps
    enc_all<<<BB / 8, 512, 0, stream>>>(x, Wa, ba, Wi, Wh, be, enc_out);

    float* hbuf[2] = { hd0, hd1 };
    for (int s = 0; s < NOUT; ++s) {
        const float* hd_in = (s == 0) ? hd0 : hbuf[(s + 1) & 1];
        float* hd_out = hbuf[s & 1];
        scores_fused<<<dim3(BB / 16, 5), 256, 0, stream>>>(
            enc_out, Wd, bd, Wl, bl, hd_in, scores, s == 0);
        softmax_ctx<<<BB / 8, 256, 0, stream>>>(scores, enc_out, ctx);
        dec_step<<<dim3(4, 64), 256, 0, stream>>>(ctx, Wdi, Wdh, bdec, hd_in, hd_out, c_d, s == 0);
        head_k<<<BB / 16, 256, 0, stream>>>(hd_out, Wf, bf, Wo, bo, out, s);
    }
}